// Round 10
// baseline (165.918 us; speedup 1.0000x reference)
//
#include <hip/hip_runtime.h>

typedef unsigned short u16;
typedef unsigned int   u32;
typedef __bf16 bf16x8 __attribute__((ext_vector_type(8)));
typedef float  f32x4  __attribute__((ext_vector_type(4)));

union U16B { int4 i4; bf16x8 b8; u16 u[8]; };
union U16Q { uint2 d2; u16 u[4]; };
union PK4  { uint2 d2; __bf16 b[4]; };

static __device__ __forceinline__ u16 f2b(float f) {
  u32 x = __float_as_uint(f);
  x += 0x7FFFu + ((x >> 16) & 1u);   // RNE (inputs finite)
  return (u16)(x >> 16);
}
static __device__ __forceinline__ float b2f(u16 s) {
  return __uint_as_float(((u32)s) << 16);
}

// async global->LDS: dest must be linear (wave-uniform base + lane*16)
#define GLOAD_LDS16(g, l) \
  __builtin_amdgcn_global_load_lds((const __attribute__((address_space(1))) u32*)(g), \
                                   (__attribute__((address_space(3))) u32*)(l), 16, 0, 0)

// ---------------- fp32 -> bf16 convert (inputs, once) ----------------
struct ConvA { const float* src[3]; u16* dst[3]; };

__global__ __launch_bounds__(256) void convA(ConvA a) {
  const float* s = a.src[blockIdx.z];
  u16*         d = a.dst[blockIdx.z];
  const size_t i = ((size_t)blockIdx.x * 256 + threadIdx.x) * 8;
  float4 f0 = *(const float4*)(s + i);
  float4 f1 = *(const float4*)(s + i + 4);
  U16B t;
  t.u[0] = f2b(f0.x); t.u[1] = f2b(f0.y); t.u[2] = f2b(f0.z); t.u[3] = f2b(f0.w);
  t.u[4] = f2b(f1.x); t.u[5] = f2b(f1.y); t.u[6] = f2b(f1.z); t.u[7] = f2b(f1.w);
  *(int4*)(d + i) = t.i4;
}

// ---------------- weight transpose + fp32->bf16 convert ----------------
struct TransA { const float* W[4]; u16* Wt[4]; };

__global__ __launch_bounds__(256) void transW(TransA a) {
  const float* W  = a.W[blockIdx.z];
  u16*         Wt = a.Wt[blockIdx.z];
  __shared__ float t[64][65];
  const int bx = blockIdx.x * 64, by = blockIdx.y * 64;
  const int tx = threadIdx.x & 63, ty = threadIdx.x >> 6;
  #pragma unroll
  for (int j = 0; j < 16; ++j) {
    int row = j * 4 + ty;
    t[row][tx] = W[(size_t)(by + row) * 1024 + bx + tx];
  }
  __syncthreads();
  #pragma unroll
  for (int j = 0; j < 16; ++j) {
    int row = j * 4 + ty;           // Wt[n][k] = W[k][n]
    Wt[(size_t)(bx + row) * 1024 + by + tx] = f2b(t[tx][row]);
  }
}

// ---------------- GEMM: C = A[M][K](bf16) * Bt[N][K]^T + bias ----------------
// 128x128 tile, BK=64, 4 waves, m97 2-barrier structure, global_load_lds
// staging (linear dest, pre-swizzled source; rule #21). Unchanged from R7-R9.
struct GemmB { const u16* A[3]; const u16* Bt[3]; const float* bias[3]; void* C[3]; int mode[3]; int cpx; };

__global__ __launch_bounds__(256) void gemm_bt(GemmB g) {
  constexpr int K = 1024, N = 1024;
  __shared__ u16 As[128 * 64];
  __shared__ u16 Bs[128 * 64];
  const int bid = blockIdx.x;
  const int lg = (bid & 7) * g.cpx + (bid >> 3);
  const int z = lg >> 8;
  const int rem = lg & 255;
  const int row0 = (rem >> 3) * 128, col0 = (rem & 7) * 128;
  const u16*   Ap   = g.A[z];
  const u16*   Bt   = g.Bt[z];
  const float* bias = g.bias[z];
  const int mode = g.mode[z];
  const int tid = threadIdx.x;
  const int wid = tid >> 6, lane = tid & 63;
  const int wr = wid >> 1, wc = wid & 1;
  const int lo = lane & 15, hi = lane >> 4;
  const int rs = tid >> 3, us = tid & 7;
  const int sw = (us ^ (rs & 7)) * 8;   // pre-swizzled source column unit

  f32x4 acc[4][4];
  const f32x4 z4 = {0.f, 0.f, 0.f, 0.f};
  #pragma unroll
  for (int i = 0; i < 4; ++i)
    #pragma unroll
    for (int j = 0; j < 4; ++j) acc[i][j] = z4;

  for (int kt = 0; kt < K / 64; ++kt) {
    __syncthreads();
    #pragma unroll
    for (int c = 0; c < 4; ++c) {
      int r = c * 32 + rs;
      GLOAD_LDS16(Ap + (size_t)(row0 + r) * K + kt * 64 + sw, &As[r * 64 + us * 8]);
      GLOAD_LDS16(Bt + (size_t)(col0 + r) * K + kt * 64 + sw, &Bs[r * 64 + us * 8]);
    }
    __syncthreads();   // compiler drains vmcnt before s_barrier
    #pragma unroll
    for (int ks = 0; ks < 2; ++ks) {
      bf16x8 af[4], bfr[4];
      #pragma unroll
      for (int mf = 0; mf < 4; ++mf) {
        int r = wr * 64 + mf * 16 + lo;
        af[mf] = *(const bf16x8*)&As[r * 64 + (((ks * 4 + hi) ^ (r & 7)) << 3)];
      }
      #pragma unroll
      for (int nf = 0; nf < 4; ++nf) {
        int r = wc * 64 + nf * 16 + lo;
        bfr[nf] = *(const bf16x8*)&Bs[r * 64 + (((ks * 4 + hi) ^ (r & 7)) << 3)];
      }
      #pragma unroll
      for (int mf = 0; mf < 4; ++mf)
        #pragma unroll
        for (int nf = 0; nf < 4; ++nf)
          acc[mf][nf] = __builtin_amdgcn_mfma_f32_16x16x32_bf16(af[mf], bfr[nf], acc[mf][nf], 0, 0, 0);
    }
  }

  #pragma unroll
  for (int nf = 0; nf < 4; ++nf) {
    int col = col0 + wc * 64 + nf * 16 + lo;
    float bv = bias[col];
    #pragma unroll
    for (int mf = 0; mf < 4; ++mf) {
      int rb = row0 + wr * 64 + mf * 16 + hi * 4;   // C/D: row=(l>>4)*4+e, col=l&15
      if (mode == 2) {
        U16Q q4;
        #pragma unroll
        for (int e = 0; e < 4; ++e) q4.u[e] = f2b(acc[mf][nf][e] + bv);
        *(uint2*)&((u16*)g.C[z])[(size_t)col * 4096 + rb] = q4.d2;   // C^T[N][4096]
      } else {
        #pragma unroll
        for (int e = 0; e < 4; ++e) {
          float v = acc[mf][nf][e] + bv;
          if (mode == 1) ((float*)g.C[z])[(size_t)(rb + e) * N + col] = v;
          else           ((u16*)g.C[z])[(size_t)(rb + e) * N + col] = f2b(v);
        }
      }
    }
  }
}

// ---------------- flash attention, split-KV x2, 32 q-rows/wave ----------------
// Diagnosis R9: LDS-throughput-bound (each ds_read_b128 fed ONE MFMA; every
// wave re-reads the same K/V tile). Fix: 2 Q fragments per wave (32 q-rows) ->
// each kf/vb read feeds 2 MFMAs; 20 reads -> 32 MFMA per iter (was 18 -> 16).
// Block = 128 q-rows; grid 1024 (x2 KV-split); LDS 32KB (4 blocks/CU = 128KB).
// Body otherwise = validated R7-R9 (swapped QK^T, PK4, gload_lds staging).
__global__ __launch_bounds__(256) void attn_fwd(const u16* __restrict__ Q,
                                                const u16* __restrict__ Kp,
                                                const u16* __restrict__ VpT,
                                                u16* __restrict__ Part,
                                                float2* __restrict__ St) {
  __shared__ u16 Ks[64 * 64];     // K tile [kk][d], XOR-swizzled rows
  __shared__ u16 Vts[64 * 64];    // V^T tile [d][kk], XOR-swizzled rows
  __shared__ u16 Ps[128 * 64];    // P tile [q][kk], per-wave rows
  const int tid = threadIdx.x;
  // decode: xcd = bid&7 owns 4 (h,b) pairs; t covers (hbsub, qb, split)
  const int bid = blockIdx.x;
  const int t = bid >> 3;                    // [0,128)
  const int hb = (bid & 7) * 4 + (t >> 5);   // 32 (h,b) pairs
  const int rem = t & 31;
  const int qb = rem >> 1;                   // [0,16)
  const int split = rem & 1;
  const int h = hb & 15, b = hb >> 4;
  const int wid = tid >> 6, lane = tid & 63;
  const int lo = lane & 15, hi = lane >> 4;
  const int rs = tid >> 3, us = tid & 7;
  const int hoff = h * 64;
  const size_t rowQ0 = (size_t)b * 2048 + (size_t)qb * 128;
  const float QSCALE = 0.125f * 1.4426950408889634f;
  const int kb0 = split * 16;

  // Q fragments (B-operand): lane holds Q[q = wid*32+mf*16+lo][d = ks*32+hi*8..]
  bf16x8 qf[2][2];
  #pragma unroll
  for (int mf = 0; mf < 2; ++mf)
    #pragma unroll
    for (int ks = 0; ks < 2; ++ks) {
      size_t r = rowQ0 + wid * 32 + mf * 16 + lo;
      U16B in; in.i4 = *(const int4*)&Q[r * 1024 + hoff + ks * 32 + hi * 8];
      U16B o;
      #pragma unroll
      for (int j = 0; j < 8; ++j) o.u[j] = f2b(b2f(in.u[j]) * QSCALE);
      qf[mf][ks] = o.b8;
    }

  f32x4 oacc[2][4];
  const f32x4 z4 = {0.f, 0.f, 0.f, 0.f};
  float m_r[2], l_r[2];
  #pragma unroll
  for (int mf = 0; mf < 2; ++mf) {
    #pragma unroll
    for (int df = 0; df < 4; ++df) oacc[mf][df] = z4;
    m_r[mf] = -1e30f; l_r[mf] = 0.f;
  }

  for (int kb = 0; kb < 16; ++kb) {
    const int kv0 = (kb0 + kb) * 64;
    __syncthreads();   // prev tile's readers done
    #pragma unroll
    for (int c = 0; c < 2; ++c) {
      int r = c * 32 + rs;
      int swu = (us ^ (r & 7)) * 8;
      GLOAD_LDS16(&Kp[((size_t)b * 2048 + kv0 + r) * 1024 + hoff + swu], &Ks[r * 64 + us * 8]);
      GLOAD_LDS16(&VpT[(size_t)(hoff + r) * 4096 + b * 2048 + kv0 + swu], &Vts[r * 64 + us * 8]);
    }
    __syncthreads();   // vmcnt drained -> tile visible

    // S^T = K Q^T : frag [mf][nf] covers kk = nf*16+hi*4+e, q = wid*32+mf*16+lo
    f32x4 sfr[2][4];
    #pragma unroll
    for (int mf = 0; mf < 2; ++mf)
      #pragma unroll
      for (int nf = 0; nf < 4; ++nf) sfr[mf][nf] = z4;
    #pragma unroll
    for (int ks = 0; ks < 2; ++ks) {
      #pragma unroll
      for (int nf = 0; nf < 4; ++nf) {
        int kk = nf * 16 + lo;
        bf16x8 kf = *(const bf16x8*)&Ks[kk * 64 + (((ks * 4 + hi) ^ (kk & 7)) << 3)];
        #pragma unroll
        for (int mf = 0; mf < 2; ++mf)   // one kf read feeds 2 MFMAs
          sfr[mf][nf] = __builtin_amdgcn_mfma_f32_16x16x32_bf16(kf, qf[mf][ks], sfr[mf][nf], 0, 0, 0);
      }
    }

    // online softmax per mf (16 values/lane, 2-shfl row reduce over hi)
    float cce[2][4];
    #pragma unroll
    for (int mf = 0; mf < 2; ++mf) {
      float pm = -1e30f;
      #pragma unroll
      for (int nf = 0; nf < 4; ++nf)
        #pragma unroll
        for (int e = 0; e < 4; ++e) pm = fmaxf(pm, sfr[mf][nf][e]);
      pm = fmaxf(pm, __shfl_xor(pm, 16));
      pm = fmaxf(pm, __shfl_xor(pm, 32));
      float mn = fmaxf(m_r[mf], pm);
      float cc = __builtin_amdgcn_exp2f(m_r[mf] - mn);
      m_r[mf] = mn;
      float ps = 0.f;
      #pragma unroll
      for (int nf = 0; nf < 4; ++nf) {
        PK4 pk;
        #pragma unroll
        for (int e = 0; e < 4; ++e) {
          float p = __builtin_amdgcn_exp2f(sfr[mf][nf][e] - mn);
          ps += p;
          pk.b[e] = (__bf16)p;     // native cast -> packed cvt
        }
        *(uint2*)&Ps[(wid * 32 + mf * 16 + lo) * 64 + ((nf * 16 + hi * 4) ^ ((lo & 7) << 3))] = pk.d2;
      }
      ps += __shfl_xor(ps, 16);
      ps += __shfl_xor(ps, 32);
      l_r[mf] = l_r[mf] * cc + ps;
      #pragma unroll
      for (int e = 0; e < 4; ++e) cce[mf][e] = __shfl(cc, hi * 4 + e);
    }

    // O = O*cc + P V   (Ps rows per-wave exclusive: no block barrier needed)
    #pragma unroll
    for (int ksp = 0; ksp < 2; ++ksp) {
      bf16x8 pa[2], vb[4];
      #pragma unroll
      for (int mf = 0; mf < 2; ++mf)
        pa[mf] = *(const bf16x8*)&Ps[(wid * 32 + mf * 16 + lo) * 64 + ((((ksp * 4 + hi) ^ (lo & 7))) << 3)];
      #pragma unroll
      for (int df = 0; df < 4; ++df) {
        int d = df * 16 + lo;
        vb[df] = *(const bf16x8*)&Vts[d * 64 + (((ksp * 4 + hi) ^ (d & 7)) << 3)];
      }
      if (ksp == 0) {
        #pragma unroll
        for (int mf = 0; mf < 2; ++mf)
          #pragma unroll
          for (int df = 0; df < 4; ++df)
            #pragma unroll
            for (int e = 0; e < 4; ++e) oacc[mf][df][e] *= cce[mf][e];
      }
      #pragma unroll
      for (int mf = 0; mf < 2; ++mf)
        #pragma unroll
        for (int df = 0; df < 4; ++df)   // one vb read feeds 2 MFMAs
          oacc[mf][df] = __builtin_amdgcn_mfma_f32_16x16x32_bf16(pa[mf], vb[df], oacc[mf][df], 0, 0, 0);
    }
  }

  // epilogue: UNNORMALIZED partial + stats (merged by attn_combine)
  u16* Po = Part + (size_t)split * 4096 * 1024;
  #pragma unroll
  for (int mf = 0; mf < 2; ++mf) {
    #pragma unroll
    for (int df = 0; df < 4; ++df)
      #pragma unroll
      for (int e = 0; e < 4; ++e) {
        size_t row = rowQ0 + wid * 32 + mf * 16 + hi * 4 + e;
        Po[row * 1024 + hoff + df * 16 + lo] = f2b(oacc[mf][df][e]);
      }
    if (hi == 0) {   // stats live at q = wid*32+mf*16+lo (hi replicas identical)
      size_t qg = (size_t)qb * 128 + wid * 32 + mf * 16 + lo;
      St[((size_t)(split * 2 + b) * 16 + h) * 2048 + qg] = make_float2(m_r[mf], l_r[mf]);
    }
  }
}

// ---------------- combine the two KV-splits ----------------
__global__ __launch_bounds__(256) void attn_combine(const u16* __restrict__ Part,
                                                    const float2* __restrict__ St,
                                                    u16* __restrict__ Op) {
  const size_t i = ((size_t)blockIdx.x * 256 + threadIdx.x) * 8;
  const int row = (int)(i >> 10);        // [0,4096)
  const int col = (int)(i & 1023);
  const int h = col >> 6;
  const int b = row >> 11, q = row & 2047;
  const float2 s0 = St[((size_t)(0 + b) * 16 + h) * 2048 + q];
  const float2 s1 = St[((size_t)(2 + b) * 16 + h) * 2048 + q];
  const float m = fmaxf(s0.x, s1.x);
  float w0 = __builtin_amdgcn_exp2f(s0.x - m);
  float w1 = __builtin_amdgcn_exp2f(s1.x - m);
  const float inv = __builtin_amdgcn_rcpf(w0 * s0.y + w1 * s1.y);
  w0 *= inv; w1 *= inv;
  U16B p0, p1, o;
  p0.i4 = *(const int4*)(Part + i);
  p1.i4 = *(const int4*)(Part + (size_t)4096 * 1024 + i);
  #pragma unroll
  for (int j = 0; j < 8; ++j)
    o.u[j] = f2b(w0 * b2f(p0.u[j]) + w1 * b2f(p1.u[j]));
  *(int4*)(Op + i) = o.i4;
}

// ---------------- launch ----------------
extern "C" void kernel_launch(void* const* d_in, const int* in_sizes, int n_in,
                              void* d_out, int out_size, void* d_ws, size_t ws_size,
                              hipStream_t stream) {
  (void)in_sizes; (void)n_in; (void)out_size;
  const size_t MB = 1024 * 1024;
  if (ws_size < 40 * MB) return;
  char* ws = (char*)d_ws;
  u16* Wqt = (u16*)(ws + 0 * MB);
  u16* Wkt = (u16*)(ws + 2 * MB);
  u16* Wvt = (u16*)(ws + 4 * MB);
  u16* Wot = (u16*)(ws + 6 * MB);
  u16* Vb  = (u16*)(ws + 8 * MB);    // bf16 value-input; later reused as Op
  u16* Qp  = (u16*)(ws + 16 * MB);
  u16* Kp  = (u16*)(ws + 24 * MB);
  u16* VpT = (u16*)(ws + 32 * MB);   // V^T [1024][4096]
  u16* Op  = (u16*)(ws + 8 * MB);    // reuse Vb space (dead after QKV GEMM)
  float2* St = (float2*)(ws + 0 * MB);      // attn stats: 1MB in dead Wqt region
  // bf16 query/key inputs parked in d_out (16MB; dead after QKV GEMM).
  // Then d_out holds attn O-partials (dead after combine), then final f32 out.
  u16* Qb = (u16*)d_out;
  u16* Kb = (u16*)d_out + (size_t)4 * MB;   // element offset: 8MB bytes
  u16* Part = (u16*)d_out;                  // 2 x 8MB bf16 O-partials

  ConvA ca;
  ca.src[0] = (const float*)d_in[0]; ca.dst[0] = Qb;
  ca.src[1] = (const float*)d_in[1]; ca.dst[1] = Kb;
  ca.src[2] = (const float*)d_in[2]; ca.dst[2] = Vb;
  hipLaunchKernelGGL(convA, dim3(2048, 1, 3), dim3(256), 0, stream, ca);

  TransA ta;
  ta.W[0] = (const float*)d_in[3]; ta.Wt[0] = Wqt;
  ta.W[1] = (const float*)d_in[5]; ta.Wt[1] = Wkt;
  ta.W[2] = (const float*)d_in[7]; ta.Wt[2] = Wvt;
  ta.W[3] = (const float*)d_in[9]; ta.Wt[3] = Wot;
  hipLaunchKernelGGL(transW, dim3(16, 16, 4), dim3(256), 0, stream, ta);

  GemmB gp;
  gp.A[0] = Qb; gp.Bt[0] = Wqt; gp.bias[0] = (const float*)d_in[4]; gp.C[0] = Qp;  gp.mode[0] = 0;
  gp.A[1] = Kb; gp.Bt[1] = Wkt; gp.bias[1] = (const float*)d_in[6]; gp.C[1] = Kp;  gp.mode[1] = 0;
  gp.A[2] = Vb; gp.Bt[2] = Wvt; gp.bias[2] = (const float*)d_in[8]; gp.C[2] = VpT; gp.mode[2] = 2;
  gp.cpx = 96;
  hipLaunchKernelGGL(gemm_bt, dim3(768), dim3(256), 0, stream, gp);

  hipLaunchKernelGGL(attn_fwd, dim3(1024), dim3(256), 0, stream, Qp, Kp, VpT, Part, St);
  hipLaunchKernelGGL(attn_combine, dim3(2048), dim3(256), 0, stream, Part, St, Op);

  GemmB gf;
  gf.A[0] = Op; gf.Bt[0] = Wot; gf.bias[0] = (const float*)d_in[10]; gf.C[0] = (void*)d_out; gf.mode[0] = 1;
  gf.A[1] = nullptr; gf.A[2] = nullptr; gf.Bt[1] = nullptr; gf.Bt[2] = nullptr;
  gf.bias[1] = nullptr; gf.bias[2] = nullptr; gf.C[1] = nullptr; gf.C[2] = nullptr;
  gf.mode[1] = 0; gf.mode[2] = 0;
  gf.cpx = 32;
  hipLaunchKernelGGL(gemm_bt, dim3(256), dim3(256), 0, stream, gf);
}

// Round 11
// 162.107 us; speedup vs baseline: 1.0235x; 1.0235x over previous
//
#include <hip/hip_runtime.h>

typedef unsigned short u16;
typedef unsigned int   u32;
typedef __bf16 bf16x8 __attribute__((ext_vector_type(8)));
typedef float  f32x4  __attribute__((ext_vector_type(4)));
typedef float  f32x16 __attribute__((ext_vector_type(16)));

union U16B { int4 i4; bf16x8 b8; u16 u[8]; };
union U16Q { uint2 d2; u16 u[4]; };
union PK2  { u32 w; __bf16 b[2]; };
union BF8W { u32 w[4]; bf16x8 v; };

static __device__ __forceinline__ u16 f2b(float f) {
  u32 x = __float_as_uint(f);
  x += 0x7FFFu + ((x >> 16) & 1u);   // RNE (inputs finite)
  return (u16)(x >> 16);
}
static __device__ __forceinline__ float b2f(u16 s) {
  return __uint_as_float(((u32)s) << 16);
}
static __device__ __forceinline__ u32 pk2(float a, float b) {
  PK2 p; p.b[0] = (__bf16)a; p.b[1] = (__bf16)b; return p.w;
}

// async global->LDS: dest must be linear (wave-uniform base + lane*16)
#define GLOAD_LDS16(g, l) \
  __builtin_amdgcn_global_load_lds((const __attribute__((address_space(1))) u32*)(g), \
                                   (__attribute__((address_space(3))) u32*)(l), 16, 0, 0)

// ---------------- fp32 -> bf16 convert (inputs, once) ----------------
struct ConvA { const float* src[3]; u16* dst[3]; };

__global__ __launch_bounds__(256) void convA(ConvA a) {
  const float* s = a.src[blockIdx.z];
  u16*         d = a.dst[blockIdx.z];
  const size_t i = ((size_t)blockIdx.x * 256 + threadIdx.x) * 8;
  float4 f0 = *(const float4*)(s + i);
  float4 f1 = *(const float4*)(s + i + 4);
  U16B t;
  t.u[0] = f2b(f0.x); t.u[1] = f2b(f0.y); t.u[2] = f2b(f0.z); t.u[3] = f2b(f0.w);
  t.u[4] = f2b(f1.x); t.u[5] = f2b(f1.y); t.u[6] = f2b(f1.z); t.u[7] = f2b(f1.w);
  *(int4*)(d + i) = t.i4;
}

// ---------------- weight transpose + fp32->bf16 convert ----------------
struct TransA { const float* W[4]; u16* Wt[4]; };

__global__ __launch_bounds__(256) void transW(TransA a) {
  const float* W  = a.W[blockIdx.z];
  u16*         Wt = a.Wt[blockIdx.z];
  __shared__ float t[64][65];
  const int bx = blockIdx.x * 64, by = blockIdx.y * 64;
  const int tx = threadIdx.x & 63, ty = threadIdx.x >> 6;
  #pragma unroll
  for (int j = 0; j < 16; ++j) {
    int row = j * 4 + ty;
    t[row][tx] = W[(size_t)(by + row) * 1024 + bx + tx];
  }
  __syncthreads();
  #pragma unroll
  for (int j = 0; j < 16; ++j) {
    int row = j * 4 + ty;           // Wt[n][k] = W[k][n]
    Wt[(size_t)(bx + row) * 1024 + by + tx] = f2b(t[tx][row]);
  }
}

// ---------------- GEMM: C = A[M][K](bf16) * Bt[N][K]^T + bias ----------------
// 128x128 tile, BK=64, 4 waves, m97 2-barrier structure, global_load_lds
// staging (linear dest, pre-swizzled source; rule #21). Unchanged from R7-R10.
struct GemmB { const u16* A[3]; const u16* Bt[3]; const float* bias[3]; void* C[3]; int mode[3]; int cpx; };

__global__ __launch_bounds__(256) void gemm_bt(GemmB g) {
  constexpr int K = 1024, N = 1024;
  __shared__ u16 As[128 * 64];
  __shared__ u16 Bs[128 * 64];
  const int bid = blockIdx.x;
  const int lg = (bid & 7) * g.cpx + (bid >> 3);
  const int z = lg >> 8;
  const int rem = lg & 255;
  const int row0 = (rem >> 3) * 128, col0 = (rem & 7) * 128;
  const u16*   Ap   = g.A[z];
  const u16*   Bt   = g.Bt[z];
  const float* bias = g.bias[z];
  const int mode = g.mode[z];
  const int tid = threadIdx.x;
  const int wid = tid >> 6, lane = tid & 63;
  const int wr = wid >> 1, wc = wid & 1;
  const int lo = lane & 15, hi = lane >> 4;
  const int rs = tid >> 3, us = tid & 7;
  const int sw = (us ^ (rs & 7)) * 8;   // pre-swizzled source column unit

  f32x4 acc[4][4];
  const f32x4 z4 = {0.f, 0.f, 0.f, 0.f};
  #pragma unroll
  for (int i = 0; i < 4; ++i)
    #pragma unroll
    for (int j = 0; j < 4; ++j) acc[i][j] = z4;

  for (int kt = 0; kt < K / 64; ++kt) {
    __syncthreads();
    #pragma unroll
    for (int c = 0; c < 4; ++c) {
      int r = c * 32 + rs;
      GLOAD_LDS16(Ap + (size_t)(row0 + r) * K + kt * 64 + sw, &As[r * 64 + us * 8]);
      GLOAD_LDS16(Bt + (size_t)(col0 + r) * K + kt * 64 + sw, &Bs[r * 64 + us * 8]);
    }
    __syncthreads();   // compiler drains vmcnt before s_barrier
    #pragma unroll
    for (int ks = 0; ks < 2; ++ks) {
      bf16x8 af[4], bfr[4];
      #pragma unroll
      for (int mf = 0; mf < 4; ++mf) {
        int r = wr * 64 + mf * 16 + lo;
        af[mf] = *(const bf16x8*)&As[r * 64 + (((ks * 4 + hi) ^ (r & 7)) << 3)];
      }
      #pragma unroll
      for (int nf = 0; nf < 4; ++nf) {
        int r = wc * 64 + nf * 16 + lo;
        bfr[nf] = *(const bf16x8*)&Bs[r * 64 + (((ks * 4 + hi) ^ (r & 7)) << 3)];
      }
      #pragma unroll
      for (int mf = 0; mf < 4; ++mf)
        #pragma unroll
        for (int nf = 0; nf < 4; ++nf)
          acc[mf][nf] = __builtin_amdgcn_mfma_f32_16x16x32_bf16(af[mf], bfr[nf], acc[mf][nf], 0, 0, 0);
    }
  }

  #pragma unroll
  for (int nf = 0; nf < 4; ++nf) {
    int col = col0 + wc * 64 + nf * 16 + lo;
    float bv = bias[col];
    #pragma unroll
    for (int mf = 0; mf < 4; ++mf) {
      int rb = row0 + wr * 64 + mf * 16 + hi * 4;   // C/D: row=(l>>4)*4+e, col=l&15
      if (mode == 2) {
        U16Q q4;
        #pragma unroll
        for (int e = 0; e < 4; ++e) q4.u[e] = f2b(acc[mf][nf][e] + bv);
        *(uint2*)&((u16*)g.C[z])[(size_t)col * 4096 + rb] = q4.d2;   // C^T[N][4096]
      } else {
        #pragma unroll
        for (int e = 0; e < 4; ++e) {
          float v = acc[mf][nf][e] + bv;
          if (mode == 1) ((float*)g.C[z])[(size_t)(rb + e) * N + col] = v;
          else           ((u16*)g.C[z])[(size_t)(rb + e) * N + col] = f2b(v);
        }
      }
    }
  }
}

// ---------------- flash attention: 32x32 MFMA, in-register softmax ----------------
// Diagnosis R8-R10: time invariant to staging/occupancy/LDS-traffic -> the
// per-iter softmax machinery (P LDS round-trip + shfl gathers) is the cost.
// m214-style fix: swapped QK^T via mfma_32x32x16 (A=K,B=Q -> S^T: lane owns
// q=lane&31, 16 kk vals; lane^32 holds the other 16) and transposed PV
// (A=V^T,B=P^T -> O^T: accumulator col=q=lane&31). Row stats = in-reg ops +
// ONE shfl_xor(32); rescale/normalize per-lane; P never touches LDS (cvt-pack
// + 8 shfl_xor + selects build the PV B-operand). No Ps tile; LDS 16KB.
// 4 waves x 32 q = 128 q/block; grid 512; KVBLK=64; staging/swizzle = R7.
__global__ __launch_bounds__(256) void attn_fwd(const u16* __restrict__ Q,
                                                const u16* __restrict__ Kp,
                                                const u16* __restrict__ VpT,
                                                u16* __restrict__ O) {
  __shared__ u16 shm[2 * 64 * 64];           // Ks | Vts; reused for epilogue
  u16* Ks  = shm;                            // K tile [kk][d], swizzled rows
  u16* Vts = shm + 64 * 64;                  // V^T tile [d][kk], swizzled rows
  const int tid = threadIdx.x;
  const int bid = blockIdx.x;                // 512 blocks: xcd=bid&7 owns 4 hb
  const int t = bid >> 3;                    // [0,64)
  const int hb = (bid & 7) * 4 + (t >> 4);   // [0,32)
  const int qb = t & 15;                     // [0,16)
  const int h = hb & 15, b = hb >> 4;
  const int wid = tid >> 6, lane = tid & 63;
  const int lq = lane & 31;                  // q (and matrix row/col) index
  const int hh = lane >> 5;                  // wave half
  const int rs = tid >> 3, us = tid & 7;
  const int hoff = h * 64;
  const size_t rowQ0 = (size_t)b * 2048 + (size_t)qb * 128;
  const int woff = wid * 32;
  const float QSCALE = 0.125f * 1.4426950408889634f;

  // Q fragments (B-operand): lane holds Q[q=lq][d = ds*16 + hh*8 + j], scaled
  bf16x8 qf[4];
  #pragma unroll
  for (int ds = 0; ds < 4; ++ds) {
    size_t r = rowQ0 + woff + lq;
    U16B in; in.i4 = *(const int4*)&Q[r * 1024 + hoff + ds * 16 + hh * 8];
    U16B o;
    #pragma unroll
    for (int j = 0; j < 8; ++j) o.u[j] = f2b(b2f(in.u[j]) * QSCALE);
    qf[ds] = o.b8;
  }

  f32x16 oacc[2];
  #pragma unroll
  for (int dt = 0; dt < 2; ++dt)
    #pragma unroll
    for (int r = 0; r < 16; ++r) oacc[dt][r] = 0.f;
  float m_r = -1e30f, l_r = 0.f;   // stats for q = lq (identical in both halves)

  const int swz = lane & 7;        // all our LDS rows have (row&7) == lane&7

  for (int kb = 0; kb < 32; ++kb) {
    const int kv0 = kb * 64;
    __syncthreads();   // prev tile's readers done
    #pragma unroll
    for (int c = 0; c < 2; ++c) {
      int r = c * 32 + rs;
      int swu = (us ^ (r & 7)) * 8;
      GLOAD_LDS16(&Kp[((size_t)b * 2048 + kv0 + r) * 1024 + hoff + swu], &Ks[r * 64 + us * 8]);
      GLOAD_LDS16(&VpT[(size_t)(hoff + r) * 4096 + b * 2048 + kv0 + swu], &Vts[r * 64 + us * 8]);
    }
    __syncthreads();   // vmcnt drained -> tile visible

    // S^T = K Q^T (two 32x32 subtiles over kk). Lane: q=lq, kk=(r&3)+8(r>>2)+4hh
    f32x16 s0, s1;
    #pragma unroll
    for (int r = 0; r < 16; ++r) { s0[r] = 0.f; s1[r] = 0.f; }
    #pragma unroll
    for (int ds = 0; ds < 4; ++ds) {
      int u = 2 * ds + hh;
      bf16x8 k0 = *(const bf16x8*)&Ks[lq * 64 + ((u ^ swz) << 3)];
      bf16x8 k1 = *(const bf16x8*)&Ks[(32 + lq) * 64 + ((u ^ swz) << 3)];
      s0 = __builtin_amdgcn_mfma_f32_32x32x16_bf16(k0, qf[ds], s0, 0, 0, 0);
      s1 = __builtin_amdgcn_mfma_f32_32x32x16_bf16(k1, qf[ds], s1, 0, 0, 0);
    }

    // online softmax, fully in-register (row q = lq)
    float pm = -1e30f;
    #pragma unroll
    for (int r = 0; r < 16; ++r) pm = fmaxf(pm, fmaxf(s0[r], s1[r]));
    pm = fmaxf(pm, __shfl_xor(pm, 32));
    float mn = fmaxf(m_r, pm);
    float cc = __builtin_amdgcn_exp2f(m_r - mn);
    m_r = mn;
    #pragma unroll
    for (int dt = 0; dt < 2; ++dt)
      #pragma unroll
      for (int r = 0; r < 16; ++r) oacc[dt][r] *= cc;
    float ps = 0.f;
    u32 c[16];
    #pragma unroll
    for (int m = 0; m < 8; ++m) {
      float e0 = __builtin_amdgcn_exp2f(s0[2 * m] - mn);
      float e1 = __builtin_amdgcn_exp2f(s0[2 * m + 1] - mn);
      ps += e0 + e1;
      c[m] = pk2(e0, e1);
    }
    #pragma unroll
    for (int m = 0; m < 8; ++m) {
      float e0 = __builtin_amdgcn_exp2f(s1[2 * m] - mn);
      float e1 = __builtin_amdgcn_exp2f(s1[2 * m + 1] - mn);
      ps += e0 + e1;
      c[8 + m] = pk2(e0, e1);
    }
    ps += __shfl_xor(ps, 32);
    l_r = l_r * cc + ps;

    // exchange halves: x[m] = lane^32's c[m]
    u32 x[16];
    #pragma unroll
    for (int m = 0; m < 16; ++m) x[m] = (u32)__shfl_xor((int)c[m], 32);

    // PV: O^T += V^T P^T  (A = V^T from LDS, B = P^T built from c/x)
    #pragma unroll
    for (int sub = 0; sub < 2; ++sub) {
      const int cb = sub * 8;
      #pragma unroll
      for (int ksp = 0; ksp < 2; ++ksp) {
        BF8W bw;
        if (ksp == 0) {
          bw.w[0] = hh ? x[cb + 2] : c[cb + 0];
          bw.w[1] = hh ? x[cb + 3] : c[cb + 1];
          bw.w[2] = hh ? c[cb + 2] : x[cb + 0];
          bw.w[3] = hh ? c[cb + 3] : x[cb + 1];
        } else {
          bw.w[0] = hh ? x[cb + 6] : c[cb + 4];
          bw.w[1] = hh ? x[cb + 7] : c[cb + 5];
          bw.w[2] = hh ? c[cb + 6] : x[cb + 4];
          bw.w[3] = hh ? c[cb + 7] : x[cb + 5];
        }
        int u = 4 * sub + 2 * ksp + hh;
        #pragma unroll
        for (int dt = 0; dt < 2; ++dt) {
          bf16x8 va = *(const bf16x8*)&Vts[(dt * 32 + lq) * 64 + ((u ^ swz) << 3)];
          oacc[dt] = __builtin_amdgcn_mfma_f32_32x32x16_bf16(va, bw.v, oacc[dt], 0, 0, 0);
        }
      }
    }
  }

  // epilogue: normalize per-lane, transpose O^T -> O through LDS, store
  float inv = __builtin_amdgcn_rcpf(l_r);
  __syncthreads();   // everyone done reading Ks/Vts
  u16* wreg = shm + wid * 2048;   // 4KB per wave: Ot[32 q][64 d] bf16, swizzled
  #pragma unroll
  for (int dt = 0; dt < 2; ++dt)
    #pragma unroll
    for (int m = 0; m < 8; ++m) {
      int bcol = ((2 * m) & 3) + 8 * (m >> 1) + 4 * hh + 32 * dt;   // d of pair
      u32 pw = pk2(oacc[dt][2 * m] * inv, oacc[dt][2 * m + 1] * inv);
      char* p = (char*)wreg + lq * 128 + (((bcol >> 3) ^ (lq & 7)) << 4) + (bcol & 7) * 2;
      *(u32*)p = pw;
    }
  #pragma unroll
  for (int pss = 0; pss < 4; ++pss) {
    int q = pss * 8 + (lane >> 3);
    int u = lane & 7;
    int4 v = *(const int4*)((const char*)wreg + q * 128 + ((u ^ (q & 7)) << 4));
    *(int4*)&O[(rowQ0 + woff + q) * 1024 + hoff + u * 8] = v;
  }
}

// ---------------- launch ----------------
extern "C" void kernel_launch(void* const* d_in, const int* in_sizes, int n_in,
                              void* d_out, int out_size, void* d_ws, size_t ws_size,
                              hipStream_t stream) {
  (void)in_sizes; (void)n_in; (void)out_size;
  const size_t MB = 1024 * 1024;
  if (ws_size < 40 * MB) return;
  char* ws = (char*)d_ws;
  u16* Wqt = (u16*)(ws + 0 * MB);
  u16* Wkt = (u16*)(ws + 2 * MB);
  u16* Wvt = (u16*)(ws + 4 * MB);
  u16* Wot = (u16*)(ws + 6 * MB);
  u16* Vb  = (u16*)(ws + 8 * MB);    // bf16 value-input; later reused as Op
  u16* Qp  = (u16*)(ws + 16 * MB);
  u16* Kp  = (u16*)(ws + 24 * MB);
  u16* VpT = (u16*)(ws + 32 * MB);   // V^T [1024][4096]
  u16* Op  = (u16*)(ws + 8 * MB);    // reuse Vb space (dead after QKV GEMM)
  // bf16 query/key inputs parked in d_out (16MB; overwritten by final GEMM)
  u16* Qb = (u16*)d_out;
  u16* Kb = (u16*)d_out + (size_t)4 * MB;   // element offset: 8MB bytes

  ConvA ca;
  ca.src[0] = (const float*)d_in[0]; ca.dst[0] = Qb;
  ca.src[1] = (const float*)d_in[1]; ca.dst[1] = Kb;
  ca.src[2] = (const float*)d_in[2]; ca.dst[2] = Vb;
  hipLaunchKernelGGL(convA, dim3(2048, 1, 3), dim3(256), 0, stream, ca);

  TransA ta;
  ta.W[0] = (const float*)d_in[3]; ta.Wt[0] = Wqt;
  ta.W[1] = (const float*)d_in[5]; ta.Wt[1] = Wkt;
  ta.W[2] = (const float*)d_in[7]; ta.Wt[2] = Wvt;
  ta.W[3] = (const float*)d_in[9]; ta.Wt[3] = Wot;
  hipLaunchKernelGGL(transW, dim3(16, 16, 4), dim3(256), 0, stream, ta);

  GemmB gp;
  gp.A[0] = Qb; gp.Bt[0] = Wqt; gp.bias[0] = (const float*)d_in[4]; gp.C[0] = Qp;  gp.mode[0] = 0;
  gp.A[1] = Kb; gp.Bt[1] = Wkt; gp.bias[1] = (const float*)d_in[6]; gp.C[1] = Kp;  gp.mode[1] = 0;
  gp.A[2] = Vb; gp.Bt[2] = Wvt; gp.bias[2] = (const float*)d_in[8]; gp.C[2] = VpT; gp.mode[2] = 2;
  gp.cpx = 96;
  hipLaunchKernelGGL(gemm_bt, dim3(768), dim3(256), 0, stream, gp);

  hipLaunchKernelGGL(attn_fwd, dim3(512), dim3(256), 0, stream, Qp, Kp, VpT, Op);

  GemmB gf;
  gf.A[0] = Op; gf.Bt[0] = Wot; gf.bias[0] = (const float*)d_in[10]; gf.C[0] = (void*)d_out; gf.mode[0] = 1;
  gf.A[1] = nullptr; gf.A[2] = nullptr; gf.Bt[1] = nullptr; gf.Bt[2] = nullptr;
  gf.bias[1] = nullptr; gf.bias[2] = nullptr; gf.C[1] = nullptr; gf.C[2] = nullptr;
  gf.mode[1] = 0; gf.mode[2] = 0;
  gf.cpx = 32;
  hipLaunchKernelGGL(gemm_bt, dim3(256), dim3(256), 0, stream, gf);
}